// Round 6
// baseline (581.017 us; speedup 1.0000x reference)
//
#include <hip/hip_runtime.h>
#include <hip/hip_fp16.h>
#include <cstdint>
#include <cstddef>

#define HEADS 4
#define HC 64
#define INC 128
#define OC 16
#define NEG 0.2f

// monotone float<->uint encoding for atomicMax on floats
__device__ inline unsigned fkey(float f) {
  unsigned b = __float_as_uint(f);
  return (b & 0x80000000u) ? ~b : (b | 0x80000000u);
}
__device__ inline float fdec(unsigned k) {
  unsigned b = (k & 0x80000000u) ? (k ^ 0x80000000u) : ~k;
  return __uint_as_float(b);
}

// ---------------- GEMM1: X[N,128] @ W1[128,256] -> H1[N,256] ----------------
__global__ __launch_bounds__(256) void k_gemm1(const float* __restrict__ X,
                                               const float* __restrict__ W,
                                               float* __restrict__ H, int N) {
  __shared__ float Ast[64][68];  // [k][row], transposed A half-tile
  __shared__ float Bs[64][64];   // [k][col]
  int t = threadIdx.x;
  int rb = blockIdx.x * 64, cb = blockIdx.y * 64;
  int tx = t & 15, ty = t >> 4;
  float acc[4][4] = {{0.f, 0.f, 0.f, 0.f}, {0.f, 0.f, 0.f, 0.f},
                     {0.f, 0.f, 0.f, 0.f}, {0.f, 0.f, 0.f, 0.f}};
  for (int kb = 0; kb < 128; kb += 64) {
    #pragma unroll
    for (int i = 0; i < 4; i++) {
      int id = t * 4 + i * 1024;
      int r = id >> 6, c = id & 63;
      int gr = rb + r; if (gr >= N) gr = N - 1;
      float4 v = *(const float4*)(X + (size_t)gr * 128 + kb + c);
      Ast[c + 0][r] = v.x; Ast[c + 1][r] = v.y;
      Ast[c + 2][r] = v.z; Ast[c + 3][r] = v.w;
    }
    #pragma unroll
    for (int i = 0; i < 4; i++) {
      int id = t * 4 + i * 1024;
      int r = id >> 6, c = id & 63;
      float4 v = *(const float4*)(W + (size_t)(kb + r) * 256 + cb + c);
      *(float4*)(&Bs[r][c]) = v;
    }
    __syncthreads();
    #pragma unroll 8
    for (int k = 0; k < 64; k++) {
      float4 a = *(const float4*)(&Ast[k][ty * 4]);
      float4 b = *(const float4*)(&Bs[k][tx * 4]);
      acc[0][0] += a.x * b.x; acc[0][1] += a.x * b.y; acc[0][2] += a.x * b.z; acc[0][3] += a.x * b.w;
      acc[1][0] += a.y * b.x; acc[1][1] += a.y * b.y; acc[1][2] += a.y * b.z; acc[1][3] += a.y * b.w;
      acc[2][0] += a.z * b.x; acc[2][1] += a.z * b.y; acc[2][2] += a.z * b.z; acc[2][3] += a.z * b.w;
      acc[3][0] += a.w * b.x; acc[3][1] += a.w * b.y; acc[3][2] += a.w * b.z; acc[3][3] += a.w * b.w;
    }
    __syncthreads();
  }
  #pragma unroll
  for (int i = 0; i < 4; i++) {
    int gr = rb + ty * 4 + i;
    if (gr < N) {
      float4 v = make_float4(acc[i][0], acc[i][1], acc[i][2], acc[i][3]);
      *(float4*)(H + (size_t)gr * 256 + cb + tx * 4) = v;
    }
  }
}

// ---- attention logits layer1 + fp16 copy of H1 (single read of H1) ---------
__global__ __launch_bounds__(256) void k_al1h(const float* __restrict__ H,
                                              const float* __restrict__ asrc,
                                              const float* __restrict__ adst,
                                              float* __restrict__ als,
                                              float* __restrict__ ald,
                                              __half* __restrict__ H16, int N) {
  int n = blockIdx.x;
  int t = threadIdx.x;
  int h = t >> 6, c = t & 63;
  float v = H[(size_t)n * 256 + t];
  H16[(size_t)n * 256 + t] = __float2half(v);
  float ps = v * asrc[t];
  float pd = v * adst[t];
  #pragma unroll
  for (int off = 32; off > 0; off >>= 1) {
    ps += __shfl_down(ps, off);
    pd += __shfl_down(pd, off);
  }
  if (c == 0) { als[n * 4 + h] = ps; ald[n * 4 + h] = pd; }
}

// ---- per-edge scores layer1 + degree count + per-(dst,head) atomic max -----
__global__ void k_score_deg1(const int* __restrict__ ei,
                             const float* __restrict__ als,
                             const float* __restrict__ ald,
                             float* __restrict__ sc, int* __restrict__ deg,
                             unsigned* __restrict__ mx1, int E, int ET) {
  int e = blockIdx.x * 256 + threadIdx.x;
  if (e >= ET) return;
  int s, d;
  if (e < E) { s = ei[e]; d = ei[E + e]; } else { s = d = e - E; }
  float4 a = *(const float4*)(als + (size_t)s * 4);
  float4 b = *(const float4*)(ald + (size_t)d * 4);
  float4 o;
  o.x = a.x + b.x; o.y = a.y + b.y; o.z = a.z + b.z; o.w = a.w + b.w;
  o.x = o.x > 0.f ? o.x : NEG * o.x;
  o.y = o.y > 0.f ? o.y : NEG * o.y;
  o.z = o.z > 0.f ? o.z : NEG * o.z;
  o.w = o.w > 0.f ? o.w : NEG * o.w;
  *(float4*)(sc + (size_t)e * 4) = o;
  atomicMax(&mx1[d * 4 + 0], fkey(o.x));
  atomicMax(&mx1[d * 4 + 1], fkey(o.y));
  atomicMax(&mx1[d * 4 + 2], fkey(o.z));
  atomicMax(&mx1[d * 4 + 3], fkey(o.w));
  atomicAdd(&deg[d], 1);
}

// ------------------------------- scan (3 kernels) ---------------------------
__global__ __launch_bounds__(256) void k_scan_partial(const int* __restrict__ deg,
                                                      int* __restrict__ bsum, int N) {
  __shared__ int sd[256];
  int t = threadIdx.x;
  int base = blockIdx.x * 1024 + t * 4;
  int s = 0;
  #pragma unroll
  for (int j = 0; j < 4; j++) { int i = base + j; s += (i < N) ? deg[i] : 0; }
  sd[t] = s;
  __syncthreads();
  for (int o = 128; o > 0; o >>= 1) {
    if (t < o) sd[t] += sd[t + o];
    __syncthreads();
  }
  if (t == 0) bsum[blockIdx.x] = sd[0];
}

__global__ void k_scan_sums(const int* __restrict__ bsum, int* __restrict__ boff,
                            int* __restrict__ offsets, int NB, int N) {
  if (threadIdx.x == 0 && blockIdx.x == 0) {
    int run = 0;
    for (int i = 0; i < NB; i++) { boff[i] = run; run += bsum[i]; }
    offsets[N] = run;
  }
}

__global__ __launch_bounds__(256) void k_scan_final(const int* __restrict__ deg,
                                                    const int* __restrict__ boff,
                                                    int* __restrict__ offsets,
                                                    int* __restrict__ cursor, int N) {
  __shared__ int sd[256];
  int t = threadIdx.x;
  int base = blockIdx.x * 1024 + t * 4;
  int v[4]; int s = 0;
  #pragma unroll
  for (int j = 0; j < 4; j++) { int i = base + j; v[j] = (i < N) ? deg[i] : 0; s += v[j]; }
  int my = s;
  sd[t] = s;
  __syncthreads();
  for (int o = 1; o < 256; o <<= 1) {
    int add = (t >= o) ? sd[t - o] : 0;
    __syncthreads();
    sd[t] += add;
    __syncthreads();
  }
  int run = sd[t] - my + boff[blockIdx.x];
  #pragma unroll
  for (int j = 0; j < 4; j++) {
    int i = base + j;
    if (i < N) { offsets[i] = run; cursor[i] = run; run += v[j]; }
  }
}

// ---- CSR fill + CSR-ordered softmax numerators p = exp(sc - max) -----------
__global__ void k_fill(const int* __restrict__ ei, int* __restrict__ cursor,
                       const float* __restrict__ sc, const unsigned* __restrict__ mx1,
                       int* __restrict__ csr_src, float* __restrict__ pw1,
                       int* __restrict__ pos_arr, int E, int ET) {
  int e = blockIdx.x * 256 + threadIdx.x;
  if (e >= ET) return;
  int s, d;
  if (e < E) { s = ei[e]; d = ei[E + e]; } else { s = d = e - E; }
  int pos = atomicAdd(&cursor[d], 1);
  csr_src[pos] = s;
  pos_arr[e] = pos;
  float4 sc4 = *(const float4*)(sc + (size_t)e * 4);
  uint4 m4 = *(const uint4*)(mx1 + (size_t)d * 4);
  float4 p;
  p.x = __expf(sc4.x - fdec(m4.x));
  p.y = __expf(sc4.y - fdec(m4.y));
  p.z = __expf(sc4.z - fdec(m4.z));
  p.w = __expf(sc4.w - fdec(m4.w));
  *(float4*)(pw1 + (size_t)pos * 4) = p;
}

// ---- layer1 aggregation: single pass, fp16 gather, 2 nodes/block -----------
__global__ __launch_bounds__(256) void k_agg1(const int* __restrict__ off,
                                              const int* __restrict__ csr_src,
                                              const float* __restrict__ pw1,
                                              const __half2* __restrict__ H16,
                                              const float* __restrict__ b1,
                                              float* __restrict__ H2, int N) {
  int t = threadIdx.x;
  int n = blockIdx.x * 2 + (t >> 7);
  if (n >= N) return;
  int tt = t & 127;          // half2 channel index 0..127
  int g = tt >> 5;           // head 0..3
  int st = off[n], en = off[n + 1];
  float ax = 0.f, ay = 0.f, s = 0.f;
  int src = (st < en) ? csr_src[st] : 0;
  for (int i = st; i < en; i++) {
    int nsrc = (i + 1 < en) ? csr_src[i + 1] : 0;
    float p = pw1[(size_t)i * 4 + g];
    __half2 hv = H16[(size_t)src * 128 + tt];
    float2 f = __half22float2(hv);
    ax += p * f.x; ay += p * f.y; s += p;
    src = nsrc;
  }
  float inv = 1.f / (s + 1e-16f);
  float2 bb = *(const float2*)(b1 + tt * 2);
  float2 o = make_float2(fmaxf(ax * inv + bb.x, 0.f), fmaxf(ay * inv + bb.y, 0.f));
  *(float2*)(H2 + (size_t)n * 256 + tt * 2) = o;
}

// ------- layer2 GEMM (256->16) + attention-logit dots, fused ----------------
__global__ __launch_bounds__(256) void k_gemm2(const float* __restrict__ H2,
                                               const float* __restrict__ W2,
                                               const float* __restrict__ as2,
                                               const float* __restrict__ ad2,
                                               float* __restrict__ Z,
                                               float* __restrict__ als2,
                                               float* __restrict__ ald2, int N) {
  __shared__ float w2s[4096];  // 256x16
  int t = threadIdx.x;
  for (int i = t; i < 4096; i += 256) w2s[i] = W2[i];
  __syncthreads();
  int n = blockIdx.x * 16 + (t >> 4);
  int c = t & 15;
  if (n >= N) return;
  const float* hp = H2 + (size_t)n * 256;
  float acc = 0.f;
  #pragma unroll 8
  for (int k = 0; k < 256; k += 4) {
    float4 hv = *(const float4*)(hp + k);
    acc += hv.x * w2s[(k + 0) * 16 + c];
    acc += hv.y * w2s[(k + 1) * 16 + c];
    acc += hv.z * w2s[(k + 2) * 16 + c];
    acc += hv.w * w2s[(k + 3) * 16 + c];
  }
  Z[(size_t)n * 16 + c] = acc;
  float ps = acc * as2[c], pd = acc * ad2[c];
  #pragma unroll
  for (int o = 8; o > 0; o >>= 1) {
    ps += __shfl_down(ps, o, 16);
    pd += __shfl_down(pd, o, 16);
  }
  if (c == 0) { als2[n] = ps; ald2[n] = pd; }
}

// ------------- per-edge scores layer 2 + atomic max -------------------------
__global__ void k_score2(const int* __restrict__ ei, const float* __restrict__ als2,
                         const float* __restrict__ ald2, float* __restrict__ sc2,
                         unsigned* __restrict__ mx2, int E, int ET) {
  int e = blockIdx.x * 256 + threadIdx.x;
  if (e >= ET) return;
  int s, d;
  if (e < E) { s = ei[e]; d = ei[E + e]; } else { s = d = e - E; }
  float v = als2[s] + ald2[d];
  v = v > 0.f ? v : NEG * v;
  sc2[e] = v;
  atomicMax(&mx2[d], fkey(v));
}

// ------------- CSR-ordered layer2 numerators --------------------------------
__global__ void k_p2(const int* __restrict__ ei, const int* __restrict__ pos_arr,
                     const float* __restrict__ sc2, const unsigned* __restrict__ mx2,
                     float* __restrict__ pw2, int E, int ET) {
  int e = blockIdx.x * 256 + threadIdx.x;
  if (e >= ET) return;
  int d = (e < E) ? ei[E + e] : e - E;
  pw2[pos_arr[e]] = __expf(sc2[e] - fdec(mx2[d]));
}

// ---- layer2 aggregation + bias + log_softmax, single pass ------------------
__global__ __launch_bounds__(256) void k_agg2(const int* __restrict__ off,
                                              const int* __restrict__ csr_src,
                                              const float* __restrict__ pw2,
                                              const float* __restrict__ Z,
                                              const float* __restrict__ b2,
                                              float* __restrict__ out, int N) {
  int t = threadIdx.x;
  int n = blockIdx.x * 16 + (t >> 4);
  if (n >= N) return;
  int c = t & 15;
  int st = off[n], en = off[n + 1];
  float s = 0.f, acc = 0.f;
  int src = (st < en) ? csr_src[st] : 0;
  for (int i = st; i < en; i++) {
    int nsrc = (i + 1 < en) ? csr_src[i + 1] : 0;
    float p = pw2[i];
    acc += p * Z[(size_t)src * 16 + c];
    s += p;
    src = nsrc;
  }
  float v = acc / (s + 1e-16f) + b2[c];
  float mx = v;
  #pragma unroll
  for (int o = 8; o > 0; o >>= 1) mx = fmaxf(mx, __shfl_xor(mx, o, 16));
  float ex = __expf(v - mx);
  float sm = ex;
  #pragma unroll
  for (int o = 8; o > 0; o >>= 1) sm += __shfl_xor(sm, o, 16);
  out[(size_t)n * 16 + c] = v - mx - logf(sm);
}

extern "C" void kernel_launch(void* const* d_in, const int* in_sizes, int n_in,
                              void* d_out, int out_size, void* d_ws, size_t ws_size,
                              hipStream_t stream) {
  const float* x   = (const float*)d_in[0];
  const int*   ei  = (const int*)d_in[1];
  const float* W1  = (const float*)d_in[2];
  const float* as1 = (const float*)d_in[3];
  const float* ad1 = (const float*)d_in[4];
  const float* b1  = (const float*)d_in[5];
  const float* W2  = (const float*)d_in[6];
  const float* as2 = (const float*)d_in[7];
  const float* ad2 = (const float*)d_in[8];
  const float* b2  = (const float*)d_in[9];
  float* out = (float*)d_out;

  int N  = in_sizes[0] / INC;   // 50000
  int E  = in_sizes[1] / 2;     // 800000
  int ET = E + N;
  int NB = (N + 1023) / 1024;

  char* w = (char*)d_ws;
  size_t off_b = 0;
  auto alloc = [&](size_t bytes) -> char* {
    size_t start = (off_b + 255) & ~(size_t)255;
    off_b = start + bytes;
    return w + start;
  };
  float*    h1   = (float*)alloc((size_t)N * 256 * 4);   // reused as H2 after k_al1h
  __half*   h16  = (__half*)alloc((size_t)N * 256 * 2);
  float*    als1 = (float*)alloc((size_t)N * 4 * 4);
  float*    ald1 = (float*)alloc((size_t)N * 4 * 4);
  float*    sc1  = (float*)alloc((size_t)ET * 4 * 4);
  // deg/mx1/mx2 contiguous -> one memset
  int*      deg  = (int*)alloc((size_t)N * 4);
  unsigned* mx1  = (unsigned*)alloc((size_t)N * 4 * 4);
  unsigned* mx2  = (unsigned*)alloc((size_t)N * 4);
  int*      offs = (int*)alloc((size_t)(N + 1) * 4);
  int*      cur  = (int*)alloc((size_t)N * 4);
  int*      bsum = (int*)alloc((size_t)NB * 4);
  int*      boff = (int*)alloc((size_t)NB * 4);
  int*      csrs = (int*)alloc((size_t)ET * 4);
  int*      posa = (int*)alloc((size_t)ET * 4);
  float*    pw1  = (float*)alloc((size_t)ET * 4 * 4);
  float*    z    = (float*)alloc((size_t)N * 16 * 4);
  float*    als2 = (float*)alloc((size_t)N * 4);
  float*    ald2 = (float*)alloc((size_t)N * 4);
  float*    sc2  = (float*)alloc((size_t)ET * 4);
  float*    pw2  = (float*)alloc((size_t)ET * 4);

  // zero deg + mx1 + mx2 in one shot (mx key 0 == -NaN == minimal)
  size_t zspan = (char*)(mx2 + N) - (char*)deg;
  hipMemsetAsync(deg, 0, zspan, stream);

  float* h2 = h1;  // buffer reuse: h1 dead after k_al1h

  k_gemm1<<<dim3((N + 63) / 64, 4), 256, 0, stream>>>(x, W1, h1, N);
  k_al1h<<<N, 256, 0, stream>>>(h1, as1, ad1, als1, ald1, h16, N);
  k_score_deg1<<<(ET + 255) / 256, 256, 0, stream>>>(ei, als1, ald1, sc1, deg, mx1, E, ET);
  k_scan_partial<<<NB, 256, 0, stream>>>(deg, bsum, N);
  k_scan_sums<<<1, 1, 0, stream>>>(bsum, boff, offs, NB, N);
  k_scan_final<<<NB, 256, 0, stream>>>(deg, boff, offs, cur, N);
  k_fill<<<(ET + 255) / 256, 256, 0, stream>>>(ei, cur, sc1, mx1, csrs, pw1, posa, E, ET);
  k_agg1<<<(N + 1) / 2, 256, 0, stream>>>(offs, csrs, pw1, (const __half2*)h16, b1, h2, N);
  k_gemm2<<<(N + 15) / 16, 256, 0, stream>>>(h2, W2, as2, ad2, z, als2, ald2, N);
  k_score2<<<(ET + 255) / 256, 256, 0, stream>>>(ei, als2, ald2, sc2, mx2, E, ET);
  k_p2<<<(ET + 255) / 256, 256, 0, stream>>>(ei, posa, sc2, mx2, pw2, E, ET);
  k_agg2<<<(N + 15) / 16, 256, 0, stream>>>(offs, csrs, pw2, z, b2, out, N);
}

// Round 7
// 301.556 us; speedup vs baseline: 1.9267x; 1.9267x over previous
//
#include <hip/hip_runtime.h>
#include <hip/hip_fp16.h>
#include <cstdint>
#include <cstddef>

#define HEADS 4
#define HC 64
#define INC 128
#define OC 16
#define NEG 0.2f

__device__ inline float lrelu(float v) { return v > 0.f ? v : NEG * v; }

// ---------------- GEMM1: X[N,128] @ W1[128,256] -> H1[N,256] ----------------
__global__ __launch_bounds__(256) void k_gemm1(const float* __restrict__ X,
                                               const float* __restrict__ W,
                                               float* __restrict__ H, int N) {
  __shared__ float Ast[64][68];  // [k][row], transposed A half-tile
  __shared__ float Bs[64][64];   // [k][col]
  int t = threadIdx.x;
  int rb = blockIdx.x * 64, cb = blockIdx.y * 64;
  int tx = t & 15, ty = t >> 4;
  float acc[4][4] = {{0.f, 0.f, 0.f, 0.f}, {0.f, 0.f, 0.f, 0.f},
                     {0.f, 0.f, 0.f, 0.f}, {0.f, 0.f, 0.f, 0.f}};
  for (int kb = 0; kb < 128; kb += 64) {
    #pragma unroll
    for (int i = 0; i < 4; i++) {
      int id = t * 4 + i * 1024;
      int r = id >> 6, c = id & 63;
      int gr = rb + r; if (gr >= N) gr = N - 1;
      float4 v = *(const float4*)(X + (size_t)gr * 128 + kb + c);
      Ast[c + 0][r] = v.x; Ast[c + 1][r] = v.y;
      Ast[c + 2][r] = v.z; Ast[c + 3][r] = v.w;
    }
    #pragma unroll
    for (int i = 0; i < 4; i++) {
      int id = t * 4 + i * 1024;
      int r = id >> 6, c = id & 63;
      float4 v = *(const float4*)(W + (size_t)(kb + r) * 256 + cb + c);
      *(float4*)(&Bs[r][c]) = v;
    }
    __syncthreads();
    #pragma unroll 8
    for (int k = 0; k < 64; k++) {
      float4 a = *(const float4*)(&Ast[k][ty * 4]);
      float4 b = *(const float4*)(&Bs[k][tx * 4]);
      acc[0][0] += a.x * b.x; acc[0][1] += a.x * b.y; acc[0][2] += a.x * b.z; acc[0][3] += a.x * b.w;
      acc[1][0] += a.y * b.x; acc[1][1] += a.y * b.y; acc[1][2] += a.y * b.z; acc[1][3] += a.y * b.w;
      acc[2][0] += a.z * b.x; acc[2][1] += a.z * b.y; acc[2][2] += a.z * b.z; acc[2][3] += a.z * b.w;
      acc[3][0] += a.w * b.x; acc[3][1] += a.w * b.y; acc[3][2] += a.w * b.z; acc[3][3] += a.w * b.w;
    }
    __syncthreads();
  }
  #pragma unroll
  for (int i = 0; i < 4; i++) {
    int gr = rb + ty * 4 + i;
    if (gr < N) {
      float4 v = make_float4(acc[i][0], acc[i][1], acc[i][2], acc[i][3]);
      *(float4*)(H + (size_t)gr * 256 + cb + tx * 4) = v;
    }
  }
}

// ---- attention logits layer1 + fp16 copy of H1 (single read of H1) ---------
__global__ __launch_bounds__(256) void k_al1h(const float* __restrict__ H,
                                              const float* __restrict__ asrc,
                                              const float* __restrict__ adst,
                                              float* __restrict__ als,
                                              float* __restrict__ ald,
                                              __half* __restrict__ H16, int N) {
  int n = blockIdx.x;
  int t = threadIdx.x;
  int h = t >> 6, c = t & 63;
  float v = H[(size_t)n * 256 + t];
  H16[(size_t)n * 256 + t] = __float2half(v);
  float ps = v * asrc[t];
  float pd = v * adst[t];
  #pragma unroll
  for (int off = 32; off > 0; off >>= 1) {
    ps += __shfl_down(ps, off);
    pd += __shfl_down(pd, off);
  }
  if (c == 0) { als[n * 4 + h] = ps; ald[n * 4 + h] = pd; }
}

// ---- degree count only ------------------------------------------------------
__global__ void k_deg(const int* __restrict__ ei, int* __restrict__ deg, int E, int ET) {
  int e = blockIdx.x * 256 + threadIdx.x;
  if (e >= ET) return;
  int d = (e < E) ? ei[E + e] : e - E;
  atomicAdd(&deg[d], 1);
}

// ------------------------------- scan (3 kernels) ---------------------------
__global__ __launch_bounds__(256) void k_scan_partial(const int* __restrict__ deg,
                                                      int* __restrict__ bsum, int N) {
  __shared__ int sd[256];
  int t = threadIdx.x;
  int base = blockIdx.x * 1024 + t * 4;
  int s = 0;
  #pragma unroll
  for (int j = 0; j < 4; j++) { int i = base + j; s += (i < N) ? deg[i] : 0; }
  sd[t] = s;
  __syncthreads();
  for (int o = 128; o > 0; o >>= 1) {
    if (t < o) sd[t] += sd[t + o];
    __syncthreads();
  }
  if (t == 0) bsum[blockIdx.x] = sd[0];
}

__global__ void k_scan_sums(const int* __restrict__ bsum, int* __restrict__ boff,
                            int* __restrict__ offsets, int NB, int N) {
  if (threadIdx.x == 0 && blockIdx.x == 0) {
    int run = 0;
    for (int i = 0; i < NB; i++) { boff[i] = run; run += bsum[i]; }
    offsets[N] = run;
  }
}

__global__ __launch_bounds__(256) void k_scan_final(const int* __restrict__ deg,
                                                    const int* __restrict__ boff,
                                                    int* __restrict__ offsets,
                                                    int* __restrict__ cursor, int N) {
  __shared__ int sd[256];
  int t = threadIdx.x;
  int base = blockIdx.x * 1024 + t * 4;
  int v[4]; int s = 0;
  #pragma unroll
  for (int j = 0; j < 4; j++) { int i = base + j; v[j] = (i < N) ? deg[i] : 0; s += v[j]; }
  int my = s;
  sd[t] = s;
  __syncthreads();
  for (int o = 1; o < 256; o <<= 1) {
    int add = (t >= o) ? sd[t - o] : 0;
    __syncthreads();
    sd[t] += add;
    __syncthreads();
  }
  int run = sd[t] - my + boff[blockIdx.x];
  #pragma unroll
  for (int j = 0; j < 4; j++) {
    int i = base + j;
    if (i < N) { offsets[i] = run; cursor[i] = run; run += v[j]; }
  }
}

// ---- CSR fill + layer1 scores + numerators p = exp(score), no max ----------
__global__ void k_fill(const int* __restrict__ ei, int* __restrict__ cursor,
                       const float* __restrict__ als, const float* __restrict__ ald,
                       int* __restrict__ csr_src, float* __restrict__ pw1,
                       int* __restrict__ pos_arr, int E, int ET) {
  int e = blockIdx.x * 256 + threadIdx.x;
  if (e >= ET) return;
  int s, d;
  if (e < E) { s = ei[e]; d = ei[E + e]; } else { s = d = e - E; }
  int pos = atomicAdd(&cursor[d], 1);
  csr_src[pos] = s;
  pos_arr[e] = pos;
  float4 a = *(const float4*)(als + (size_t)s * 4);
  float4 b = *(const float4*)(ald + (size_t)d * 4);
  float4 p;
  p.x = __expf(lrelu(a.x + b.x));
  p.y = __expf(lrelu(a.y + b.y));
  p.z = __expf(lrelu(a.z + b.z));
  p.w = __expf(lrelu(a.w + b.w));
  *(float4*)(pw1 + (size_t)pos * 4) = p;
}

// ---- layer1 aggregation: 32 threads/node, 16B gathers, unroll x4 -----------
__device__ inline void acc8(float4 v, float p, float* a, float& s) {
  __half2 h0 = __builtin_bit_cast(__half2, v.x);
  __half2 h1 = __builtin_bit_cast(__half2, v.y);
  __half2 h2 = __builtin_bit_cast(__half2, v.z);
  __half2 h3 = __builtin_bit_cast(__half2, v.w);
  float2 f0 = __half22float2(h0), f1 = __half22float2(h1);
  float2 f2 = __half22float2(h2), f3 = __half22float2(h3);
  a[0] += p * f0.x; a[1] += p * f0.y; a[2] += p * f1.x; a[3] += p * f1.y;
  a[4] += p * f2.x; a[5] += p * f2.y; a[6] += p * f3.x; a[7] += p * f3.y;
  s += p;
}

__global__ __launch_bounds__(256) void k_agg1(const int* __restrict__ off,
                                              const int* __restrict__ csr_src,
                                              const float* __restrict__ pw1,
                                              const float4* __restrict__ H16,
                                              const float* __restrict__ b1,
                                              float* __restrict__ H2, int N) {
  int t = threadIdx.x;
  int n = blockIdx.x * 8 + (t >> 5);
  if (n >= N) return;
  int lane = t & 31;       // covers fp16 channels lane*8 .. lane*8+7
  int g = lane >> 3;       // head
  int st = off[n], en = off[n + 1];
  float a[8] = {0.f, 0.f, 0.f, 0.f, 0.f, 0.f, 0.f, 0.f};
  float s = 0.f;
  int i = st;
  for (; i + 4 <= en; i += 4) {
    int s0 = csr_src[i], s1 = csr_src[i + 1], s2 = csr_src[i + 2], s3 = csr_src[i + 3];
    float p0 = pw1[(size_t)i * 4 + g];
    float p1 = pw1[(size_t)(i + 1) * 4 + g];
    float p2 = pw1[(size_t)(i + 2) * 4 + g];
    float p3 = pw1[(size_t)(i + 3) * 4 + g];
    float4 v0 = H16[(size_t)s0 * 32 + lane];
    float4 v1 = H16[(size_t)s1 * 32 + lane];
    float4 v2 = H16[(size_t)s2 * 32 + lane];
    float4 v3 = H16[(size_t)s3 * 32 + lane];
    acc8(v0, p0, a, s); acc8(v1, p1, a, s); acc8(v2, p2, a, s); acc8(v3, p3, a, s);
  }
  for (; i < en; i++) {
    int s0 = csr_src[i];
    float p0 = pw1[(size_t)i * 4 + g];
    float4 v0 = H16[(size_t)s0 * 32 + lane];
    acc8(v0, p0, a, s);
  }
  float inv = 1.f / (s + 1e-16f);
  int c0 = lane * 8;
  float4 bb0 = *(const float4*)(b1 + c0);
  float4 bb1 = *(const float4*)(b1 + c0 + 4);
  float4 o0 = make_float4(fmaxf(a[0] * inv + bb0.x, 0.f), fmaxf(a[1] * inv + bb0.y, 0.f),
                          fmaxf(a[2] * inv + bb0.z, 0.f), fmaxf(a[3] * inv + bb0.w, 0.f));
  float4 o1 = make_float4(fmaxf(a[4] * inv + bb1.x, 0.f), fmaxf(a[5] * inv + bb1.y, 0.f),
                          fmaxf(a[6] * inv + bb1.z, 0.f), fmaxf(a[7] * inv + bb1.w, 0.f));
  float* hp = H2 + (size_t)n * 256 + c0;
  *(float4*)(hp) = o0;
  *(float4*)(hp + 4) = o1;
}

// ------- layer2 GEMM (256->16) + attention-logit dots, fused ----------------
__global__ __launch_bounds__(256) void k_gemm2(const float* __restrict__ H2,
                                               const float* __restrict__ W2,
                                               const float* __restrict__ as2,
                                               const float* __restrict__ ad2,
                                               float* __restrict__ Z,
                                               float* __restrict__ als2,
                                               float* __restrict__ ald2, int N) {
  __shared__ float w2s[4096];  // 256x16
  int t = threadIdx.x;
  for (int i = t; i < 4096; i += 256) w2s[i] = W2[i];
  __syncthreads();
  int n = blockIdx.x * 16 + (t >> 4);
  int c = t & 15;
  if (n >= N) return;
  const float* hp = H2 + (size_t)n * 256;
  float acc = 0.f;
  #pragma unroll 8
  for (int k = 0; k < 256; k += 4) {
    float4 hv = *(const float4*)(hp + k);
    acc += hv.x * w2s[(k + 0) * 16 + c];
    acc += hv.y * w2s[(k + 1) * 16 + c];
    acc += hv.z * w2s[(k + 2) * 16 + c];
    acc += hv.w * w2s[(k + 3) * 16 + c];
  }
  Z[(size_t)n * 16 + c] = acc;
  float ps = acc * as2[c], pd = acc * ad2[c];
  #pragma unroll
  for (int o = 8; o > 0; o >>= 1) {
    ps += __shfl_down(ps, o, 16);
    pd += __shfl_down(pd, o, 16);
  }
  if (c == 0) { als2[n] = ps; ald2[n] = pd; }
}

// ---- layer2: score + exp, CSR-ordered, single pass (no max) ----------------
__global__ void k_score2p(const int* __restrict__ ei, const int* __restrict__ pos_arr,
                          const float* __restrict__ als2, const float* __restrict__ ald2,
                          float* __restrict__ pw2, int E, int ET) {
  int e = blockIdx.x * 256 + threadIdx.x;
  if (e >= ET) return;
  int s, d;
  if (e < E) { s = ei[e]; d = ei[E + e]; } else { s = d = e - E; }
  float v = lrelu(als2[s] + ald2[d]);
  pw2[pos_arr[e]] = __expf(v);
}

// ---- layer2 aggregation + bias + log_softmax, unroll x4 --------------------
__global__ __launch_bounds__(256) void k_agg2(const int* __restrict__ off,
                                              const int* __restrict__ csr_src,
                                              const float* __restrict__ pw2,
                                              const float* __restrict__ Z,
                                              const float* __restrict__ b2,
                                              float* __restrict__ out, int N) {
  int t = threadIdx.x;
  int n = blockIdx.x * 16 + (t >> 4);
  if (n >= N) return;
  int c = t & 15;
  int st = off[n], en = off[n + 1];
  float s = 0.f, acc = 0.f;
  int i = st;
  for (; i + 4 <= en; i += 4) {
    int s0 = csr_src[i], s1 = csr_src[i + 1], s2 = csr_src[i + 2], s3 = csr_src[i + 3];
    float p0 = pw2[i], p1 = pw2[i + 1], p2 = pw2[i + 2], p3 = pw2[i + 3];
    float z0 = Z[(size_t)s0 * 16 + c];
    float z1 = Z[(size_t)s1 * 16 + c];
    float z2 = Z[(size_t)s2 * 16 + c];
    float z3 = Z[(size_t)s3 * 16 + c];
    acc += p0 * z0 + p1 * z1 + p2 * z2 + p3 * z3;
    s += p0 + p1 + p2 + p3;
  }
  for (; i < en; i++) {
    int s0 = csr_src[i];
    float p0 = pw2[i];
    acc += p0 * Z[(size_t)s0 * 16 + c];
    s += p0;
  }
  float v = acc / (s + 1e-16f) + b2[c];
  float mx = v;
  #pragma unroll
  for (int o = 8; o > 0; o >>= 1) mx = fmaxf(mx, __shfl_xor(mx, o, 16));
  float ex = __expf(v - mx);
  float sm = ex;
  #pragma unroll
  for (int o = 8; o > 0; o >>= 1) sm += __shfl_xor(sm, o, 16);
  out[(size_t)n * 16 + c] = v - mx - logf(sm);
}

extern "C" void kernel_launch(void* const* d_in, const int* in_sizes, int n_in,
                              void* d_out, int out_size, void* d_ws, size_t ws_size,
                              hipStream_t stream) {
  const float* x   = (const float*)d_in[0];
  const int*   ei  = (const int*)d_in[1];
  const float* W1  = (const float*)d_in[2];
  const float* as1 = (const float*)d_in[3];
  const float* ad1 = (const float*)d_in[4];
  const float* b1  = (const float*)d_in[5];
  const float* W2  = (const float*)d_in[6];
  const float* as2 = (const float*)d_in[7];
  const float* ad2 = (const float*)d_in[8];
  const float* b2  = (const float*)d_in[9];
  float* out = (float*)d_out;

  int N  = in_sizes[0] / INC;   // 50000
  int E  = in_sizes[1] / 2;     // 800000
  int ET = E + N;
  int NB = (N + 1023) / 1024;

  char* w = (char*)d_ws;
  size_t off_b = 0;
  auto alloc = [&](size_t bytes) -> char* {
    size_t start = (off_b + 255) & ~(size_t)255;
    off_b = start + bytes;
    return w + start;
  };
  float*    h1   = (float*)alloc((size_t)N * 256 * 4);   // reused as H2 after k_al1h
  __half*   h16  = (__half*)alloc((size_t)N * 256 * 2);
  float*    als1 = (float*)alloc((size_t)N * 4 * 4);
  float*    ald1 = (float*)alloc((size_t)N * 4 * 4);
  int*      deg  = (int*)alloc((size_t)N * 4);
  int*      offs = (int*)alloc((size_t)(N + 1) * 4);
  int*      cur  = (int*)alloc((size_t)N * 4);
  int*      bsum = (int*)alloc((size_t)NB * 4);
  int*      boff = (int*)alloc((size_t)NB * 4);
  int*      csrs = (int*)alloc((size_t)ET * 4);
  int*      posa = (int*)alloc((size_t)ET * 4);
  float*    pw1  = (float*)alloc((size_t)ET * 4 * 4);
  float*    z    = (float*)alloc((size_t)N * 16 * 4);
  float*    als2 = (float*)alloc((size_t)N * 4);
  float*    ald2 = (float*)alloc((size_t)N * 4);
  float*    pw2  = (float*)alloc((size_t)ET * 4);

  hipMemsetAsync(deg, 0, (size_t)N * 4, stream);

  float* h2 = h1;  // buffer reuse: h1 dead after k_al1h

  k_gemm1<<<dim3((N + 63) / 64, 4), 256, 0, stream>>>(x, W1, h1, N);
  k_al1h<<<N, 256, 0, stream>>>(h1, as1, ad1, als1, ald1, h16, N);
  k_deg<<<(ET + 255) / 256, 256, 0, stream>>>(ei, deg, E, ET);
  k_scan_partial<<<NB, 256, 0, stream>>>(deg, bsum, N);
  k_scan_sums<<<1, 1, 0, stream>>>(bsum, boff, offs, NB, N);
  k_scan_final<<<NB, 256, 0, stream>>>(deg, boff, offs, cur, N);
  k_fill<<<(ET + 255) / 256, 256, 0, stream>>>(ei, cur, als1, ald1, csrs, pw1, posa, E, ET);
  k_agg1<<<(N + 7) / 8, 256, 0, stream>>>(offs, csrs, pw1, (const float4*)h16, b1, h2, N);
  k_gemm2<<<(N + 15) / 16, 256, 0, stream>>>(h2, W2, as2, ad2, z, als2, ald2, N);
  k_score2p<<<(ET + 255) / 256, 256, 0, stream>>>(ei, posa, als2, ald2, pw2, E, ET);
  k_agg2<<<(N + 15) / 16, 256, 0, stream>>>(offs, csrs, pw2, z, b2, out, N);
}

// Round 8
// 249.536 us; speedup vs baseline: 2.3284x; 1.2085x over previous
//
#include <hip/hip_runtime.h>
#include <hip/hip_fp16.h>
#include <cstdint>
#include <cstddef>

#define NEG 0.2f

typedef _Float16 f16x8 __attribute__((ext_vector_type(8)));
typedef float f32x4 __attribute__((ext_vector_type(4)));

__device__ inline float lrelu(float v) { return v > 0.f ? v : NEG * v; }

// ---- pre-swizzle W1 (f32 [128][256]) into per-lane MFMA fragment order -----
// tau = (ks*16 + ct)*64 + l ; 8 halves: j<4 -> k = ks*32 + (l>>4)*4 + j
//                             j>=4 -> k = ks*32 + 16 + (l>>4)*4 + (j-4)
__global__ void k_swzW(const float* __restrict__ W1, f16x8* __restrict__ W1s) {
  int tau = blockIdx.x * 256 + threadIdx.x;
  if (tau >= 4096) return;
  int l = tau & 63, ct = (tau >> 6) & 15, ks = tau >> 10;
  int col = ct * 16 + (l & 15);
  f16x8 v;
  #pragma unroll
  for (int j = 0; j < 8; j++) {
    int k = ks * 32 + ((j < 4) ? ((l >> 4) * 4 + j) : (16 + (l >> 4) * 4 + (j - 4)));
    v[j] = (_Float16)W1[k * 256 + col];
  }
  W1s[tau] = v;
}

// ---- fused GEMM1 (MFMA fp16) + attention logits + fp16 H output ------------
// block: 256 thr = 4 waves; tile 64 rows x 256 cols; wave w -> cols [64w,64w+64) = head w
__global__ __launch_bounds__(256) void k_gemm1f(const float* __restrict__ X,
                                                const f16x8* __restrict__ W1s,
                                                const float* __restrict__ as1,
                                                const float* __restrict__ ad1,
                                                __half* __restrict__ H16,
                                                float* __restrict__ als,
                                                float* __restrict__ ald, int N) {
  __shared__ __align__(16) char lds[32768];  // A-tile 16KB, then reused as 32KB h-tile
  _Float16* A = (_Float16*)lds;
  int t = threadIdx.x;
  int rb = blockIdx.x * 64;
  int l = t & 63, wv = t >> 6;

  // stage A: X[rb..rb+63][0..127] f32 -> fp16, XOR-swizzled 16B granules
  #pragma unroll
  for (int i = 0; i < 8; i++) {
    int idx = i * 256 + t;
    int row = idx >> 5, q = idx & 31;
    int gr = rb + row; if (gr >= N) gr = N - 1;
    float4 xv = *(const float4*)(X + (size_t)gr * 128 + q * 4);
    int ks = q >> 3, g = q & 3, hg = (q >> 2) & 1;
    int gran = (ks * 4 + g) ^ (row & 7);
    _Float16* dst = A + row * 128 + gran * 8 + hg * 4;
    dst[0] = (_Float16)xv.x; dst[1] = (_Float16)xv.y;
    dst[2] = (_Float16)xv.z; dst[3] = (_Float16)xv.w;
  }
  __syncthreads();

  f32x4 acc[4][4] = {};  // [row-tile][col-tile]
  #pragma unroll
  for (int ks = 0; ks < 4; ks++) {
    f16x8 bfr[4];
    #pragma unroll
    for (int ct = 0; ct < 4; ct++)
      bfr[ct] = W1s[(ks * 16 + wv * 4 + ct) * 64 + l];
    #pragma unroll
    for (int rt = 0; rt < 4; rt++) {
      int row = rt * 16 + (l & 15);
      int gran = (ks * 4 + (l >> 4)) ^ (row & 7);
      f16x8 afr = *(const f16x8*)(A + row * 128 + gran * 8);
      #pragma unroll
      for (int ct = 0; ct < 4; ct++)
        acc[rt][ct] = __builtin_amdgcn_mfma_f32_16x16x32_f16(afr, bfr[ct], acc[rt][ct], 0, 0, 0);
    }
  }

  // als/ald for head wv directly from accumulators (C/D: col=l&15, row=(l>>4)*4+reg)
  float asv[4], adv[4];
  #pragma unroll
  for (int ct = 0; ct < 4; ct++) {
    asv[ct] = as1[wv * 64 + ct * 16 + (l & 15)];
    adv[ct] = ad1[wv * 64 + ct * 16 + (l & 15)];
  }
  #pragma unroll
  for (int rt = 0; rt < 4; rt++) {
    #pragma unroll
    for (int j = 0; j < 4; j++) {
      float ps = 0.f, pd = 0.f;
      #pragma unroll
      for (int ct = 0; ct < 4; ct++) {
        ps += acc[rt][ct][j] * asv[ct];
        pd += acc[rt][ct][j] * adv[ct];
      }
      ps += __shfl_xor(ps, 1); ps += __shfl_xor(ps, 2);
      ps += __shfl_xor(ps, 4); ps += __shfl_xor(ps, 8);
      pd += __shfl_xor(pd, 1); pd += __shfl_xor(pd, 2);
      pd += __shfl_xor(pd, 4); pd += __shfl_xor(pd, 8);
      if ((l & 15) == 0) {
        int gr = rb + rt * 16 + (l >> 4) * 4 + j;
        if (gr < N) { als[gr * 4 + wv] = ps; ald[gr * 4 + wv] = pd; }
      }
    }
  }

  __syncthreads();  // all A reads done; reuse LDS as h-tile
  _Float16* HL = (_Float16*)lds;  // [64][256] fp16, 16B-granule XOR swizzle
  #pragma unroll
  for (int rt = 0; rt < 4; rt++) {
    #pragma unroll
    for (int j = 0; j < 4; j++) {
      int row = rt * 16 + (l >> 4) * 4 + j;
      #pragma unroll
      for (int ct = 0; ct < 4; ct++) {
        int col = wv * 64 + ct * 16 + (l & 15);
        int g2 = (col >> 3) ^ ((row & 7) << 2);
        HL[row * 256 + g2 * 8 + (col & 7)] = (_Float16)acc[rt][ct][j];
      }
    }
  }
  __syncthreads();
  #pragma unroll
  for (int i = 0; i < 8; i++) {
    int idx = i * 256 + t;
    int row = idx >> 5, g = idx & 31;
    int g2 = g ^ ((row & 7) << 2);
    f32x4 v = *(const f32x4*)(HL + row * 256 + g2 * 8);
    int gr = rb + row;
    if (gr < N) *(f32x4*)((char*)H16 + (size_t)gr * 512 + g * 16) = v;
  }
}

// ---- degree count -----------------------------------------------------------
__global__ void k_deg(const int* __restrict__ ei, int* __restrict__ deg, int E, int ET) {
  int e = blockIdx.x * 256 + threadIdx.x;
  if (e >= ET) return;
  int d = (e < E) ? ei[E + e] : e - E;
  atomicAdd(&deg[d], 1);
}

// ------------------------------- scan (3 kernels) ---------------------------
__global__ __launch_bounds__(256) void k_scan_partial(const int* __restrict__ deg,
                                                      int* __restrict__ bsum, int N) {
  __shared__ int sd[256];
  int t = threadIdx.x;
  int base = blockIdx.x * 1024 + t * 4;
  int s = 0;
  #pragma unroll
  for (int j = 0; j < 4; j++) { int i = base + j; s += (i < N) ? deg[i] : 0; }
  sd[t] = s;
  __syncthreads();
  for (int o = 128; o > 0; o >>= 1) {
    if (t < o) sd[t] += sd[t + o];
    __syncthreads();
  }
  if (t == 0) bsum[blockIdx.x] = sd[0];
}

__global__ void k_scan_sums(const int* __restrict__ bsum, int* __restrict__ boff,
                            int* __restrict__ offsets, int NB, int N) {
  if (threadIdx.x == 0 && blockIdx.x == 0) {
    int run = 0;
    for (int i = 0; i < NB; i++) { boff[i] = run; run += bsum[i]; }
    offsets[N] = run;
  }
}

__global__ __launch_bounds__(256) void k_scan_final(const int* __restrict__ deg,
                                                    const int* __restrict__ boff,
                                                    int* __restrict__ offsets,
                                                    int* __restrict__ cursor, int N) {
  __shared__ int sd[256];
  int t = threadIdx.x;
  int base = blockIdx.x * 1024 + t * 4;
  int v[4]; int s = 0;
  #pragma unroll
  for (int j = 0; j < 4; j++) { int i = base + j; v[j] = (i < N) ? deg[i] : 0; s += v[j]; }
  int my = s;
  sd[t] = s;
  __syncthreads();
  for (int o = 1; o < 256; o <<= 1) {
    int add = (t >= o) ? sd[t - o] : 0;
    __syncthreads();
    sd[t] += add;
    __syncthreads();
  }
  int run = sd[t] - my + boff[blockIdx.x];
  #pragma unroll
  for (int j = 0; j < 4; j++) {
    int i = base + j;
    if (i < N) { offsets[i] = run; cursor[i] = run; run += v[j]; }
  }
}

// ---- CSR fill + layer1 numerators p = exp(lrelu(score)), no max ------------
__global__ void k_fill(const int* __restrict__ ei, int* __restrict__ cursor,
                       const float* __restrict__ als, const float* __restrict__ ald,
                       int* __restrict__ csr_src, float* __restrict__ pw1,
                       int* __restrict__ pos_arr, int E, int ET) {
  int e = blockIdx.x * 256 + threadIdx.x;
  if (e >= ET) return;
  int s, d;
  if (e < E) { s = ei[e]; d = ei[E + e]; } else { s = d = e - E; }
  int pos = atomicAdd(&cursor[d], 1);
  csr_src[pos] = s;
  pos_arr[e] = pos;
  float4 a = *(const float4*)(als + (size_t)s * 4);
  float4 b = *(const float4*)(ald + (size_t)d * 4);
  float4 p;
  p.x = __expf(lrelu(a.x + b.x));
  p.y = __expf(lrelu(a.y + b.y));
  p.z = __expf(lrelu(a.z + b.z));
  p.w = __expf(lrelu(a.w + b.w));
  *(float4*)(pw1 + (size_t)pos * 4) = p;
}

// ---- layer1 aggregation: 32 thr/node, 16B gathers, unroll x4, fp16 out -----
__device__ inline void acc8(float4 v, float p, float* a, float& s) {
  __half2 h0 = __builtin_bit_cast(__half2, v.x);
  __half2 h1 = __builtin_bit_cast(__half2, v.y);
  __half2 h2 = __builtin_bit_cast(__half2, v.z);
  __half2 h3 = __builtin_bit_cast(__half2, v.w);
  float2 f0 = __half22float2(h0), f1 = __half22float2(h1);
  float2 f2 = __half22float2(h2), f3 = __half22float2(h3);
  a[0] += p * f0.x; a[1] += p * f0.y; a[2] += p * f1.x; a[3] += p * f1.y;
  a[4] += p * f2.x; a[5] += p * f2.y; a[6] += p * f3.x; a[7] += p * f3.y;
  s += p;
}

__global__ __launch_bounds__(256) void k_agg1(const int* __restrict__ off,
                                              const int* __restrict__ csr_src,
                                              const float* __restrict__ pw1,
                                              const float4* __restrict__ H16,
                                              const float* __restrict__ b1,
                                              __half* __restrict__ H2, int N) {
  int t = threadIdx.x;
  int n = blockIdx.x * 8 + (t >> 5);
  if (n >= N) return;
  int lane = t & 31;       // fp16 channels lane*8 .. lane*8+7
  int g = lane >> 3;       // head
  int st = off[n], en = off[n + 1];
  float a[8] = {0.f, 0.f, 0.f, 0.f, 0.f, 0.f, 0.f, 0.f};
  float s = 0.f;
  int i = st;
  for (; i + 4 <= en; i += 4) {
    int s0 = csr_src[i], s1 = csr_src[i + 1], s2 = csr_src[i + 2], s3 = csr_src[i + 3];
    float p0 = pw1[(size_t)i * 4 + g];
    float p1 = pw1[(size_t)(i + 1) * 4 + g];
    float p2 = pw1[(size_t)(i + 2) * 4 + g];
    float p3 = pw1[(size_t)(i + 3) * 4 + g];
    float4 v0 = H16[(size_t)s0 * 32 + lane];
    float4 v1 = H16[(size_t)s1 * 32 + lane];
    float4 v2 = H16[(size_t)s2 * 32 + lane];
    float4 v3 = H16[(size_t)s3 * 32 + lane];
    acc8(v0, p0, a, s); acc8(v1, p1, a, s); acc8(v2, p2, a, s); acc8(v3, p3, a, s);
  }
  for (; i < en; i++) {
    int s0 = csr_src[i];
    float p0 = pw1[(size_t)i * 4 + g];
    float4 v0 = H16[(size_t)s0 * 32 + lane];
    acc8(v0, p0, a, s);
  }
  float inv = 1.f / (s + 1e-16f);
  int c0 = lane * 8;
  float4 bb0 = *(const float4*)(b1 + c0);
  float4 bb1 = *(const float4*)(b1 + c0 + 4);
  f16x8 o;
  o[0] = (_Float16)fmaxf(a[0] * inv + bb0.x, 0.f);
  o[1] = (_Float16)fmaxf(a[1] * inv + bb0.y, 0.f);
  o[2] = (_Float16)fmaxf(a[2] * inv + bb0.z, 0.f);
  o[3] = (_Float16)fmaxf(a[3] * inv + bb0.w, 0.f);
  o[4] = (_Float16)fmaxf(a[4] * inv + bb1.x, 0.f);
  o[5] = (_Float16)fmaxf(a[5] * inv + bb1.y, 0.f);
  o[6] = (_Float16)fmaxf(a[6] * inv + bb1.z, 0.f);
  o[7] = (_Float16)fmaxf(a[7] * inv + bb1.w, 0.f);
  *(f16x8*)((char*)H2 + (size_t)n * 512 + lane * 16) = o;
}

// ------- layer2 GEMM (256->16, fp16 in) + attention-logit dots --------------
__global__ __launch_bounds__(256) void k_gemm2(const __half* __restrict__ H2,
                                               const float* __restrict__ W2,
                                               const float* __restrict__ as2,
                                               const float* __restrict__ ad2,
                                               float* __restrict__ Z,
                                               float* __restrict__ als2,
                                               float* __restrict__ ald2, int N) {
  __shared__ float w2s[4096];  // 256x16
  int t = threadIdx.x;
  for (int i = t; i < 4096; i += 256) w2s[i] = W2[i];
  __syncthreads();
  int n = blockIdx.x * 16 + (t >> 4);
  int c = t & 15;
  if (n >= N) return;
  const f16x8* hp = (const f16x8*)((const char*)H2 + (size_t)n * 512);
  float acc = 0.f;
  #pragma unroll 8
  for (int kb = 0; kb < 32; kb++) {
    f16x8 hv = hp[kb];
    #pragma unroll
    for (int j = 0; j < 8; j++)
      acc += (float)hv[j] * w2s[(kb * 8 + j) * 16 + c];
  }
  Z[(size_t)n * 16 + c] = acc;
  float ps = acc * as2[c], pd = acc * ad2[c];
  #pragma unroll
  for (int o = 8; o > 0; o >>= 1) {
    ps += __shfl_down(ps, o, 16);
    pd += __shfl_down(pd, o, 16);
  }
  if (c == 0) { als2[n] = ps; ald2[n] = pd; }
}

// ---- layer2: score + exp, CSR-ordered, single pass (no max) ----------------
__global__ void k_score2p(const int* __restrict__ ei, const int* __restrict__ pos_arr,
                          const float* __restrict__ als2, const float* __restrict__ ald2,
                          float* __restrict__ pw2, int E, int ET) {
  int e = blockIdx.x * 256 + threadIdx.x;
  if (e >= ET) return;
  int s, d;
  if (e < E) { s = ei[e]; d = ei[E + e]; } else { s = d = e - E; }
  float v = lrelu(als2[s] + ald2[d]);
  pw2[pos_arr[e]] = __expf(v);
}

// ---- layer2 aggregation + bias + log_softmax, unroll x4 --------------------
__global__ __launch_bounds__(256) void k_agg2(const int* __restrict__ off,
                                              const int* __restrict__ csr_src,
                                              const float* __restrict__ pw2,
                                              const float* __restrict__ Z,
                                              const float* __restrict__ b2,
                                              float* __restrict__ out, int N) {
  int t = threadIdx.x;
  int n = blockIdx.x * 16 + (t >> 4);
  if (n >= N) return;
  int c = t & 15;
  int st = off[n], en = off[n + 1];
  float s = 0.f, acc = 0.f;
  int i = st;
  for (; i + 4 <= en; i += 4) {
    int s0 = csr_src[i], s1 = csr_src[i + 1], s2 = csr_src[i + 2], s3 = csr_src[i + 3];
    float p0 = pw2[i], p1 = pw2[i + 1], p2 = pw2[i + 2], p3 = pw2[i + 3];
    float z0 = Z[(size_t)s0 * 16 + c];
    float z1 = Z[(size_t)s1 * 16 + c];
    float z2 = Z[(size_t)s2 * 16 + c];
    float z3 = Z[(size_t)s3 * 16 + c];
    acc += p0 * z0 + p1 * z1 + p2 * z2 + p3 * z3;
    s += p0 + p1 + p2 + p3;
  }
  for (; i < en; i++) {
    int s0 = csr_src[i];
    float p0 = pw2[i];
    acc += p0 * Z[(size_t)s0 * 16 + c];
    s += p0;
  }
  float v = acc / (s + 1e-16f) + b2[c];
  float mx = v;
  #pragma unroll
  for (int o = 8; o > 0; o >>= 1) mx = fmaxf(mx, __shfl_xor(mx, o, 16));
  float ex = __expf(v - mx);
  float sm = ex;
  #pragma unroll
  for (int o = 8; o > 0; o >>= 1) sm += __shfl_xor(sm, o, 16);
  out[(size_t)n * 16 + c] = v - mx - logf(sm);
}

extern "C" void kernel_launch(void* const* d_in, const int* in_sizes, int n_in,
                              void* d_out, int out_size, void* d_ws, size_t ws_size,
                              hipStream_t stream) {
  const float* x   = (const float*)d_in[0];
  const int*   ei  = (const int*)d_in[1];
  const float* W1  = (const float*)d_in[2];
  const float* as1 = (const float*)d_in[3];
  const float* ad1 = (const float*)d_in[4];
  const float* b1  = (const float*)d_in[5];
  const float* W2  = (const float*)d_in[6];
  const float* as2 = (const float*)d_in[7];
  const float* ad2 = (const float*)d_in[8];
  const float* b2  = (const float*)d_in[9];
  float* out = (float*)d_out;

  int N  = in_sizes[0] / 128;   // 50000
  int E  = in_sizes[1] / 2;     // 800000
  int ET = E + N;
  int NB = (N + 1023) / 1024;

  char* w = (char*)d_ws;
  size_t off_b = 0;
  auto alloc = [&](size_t bytes) -> char* {
    size_t start = (off_b + 255) & ~(size_t)255;
    off_b = start + bytes;
    return w + start;
  };
  __half*   h16  = (__half*)alloc((size_t)N * 256 * 2);
  __half*   h2   = (__half*)alloc((size_t)N * 256 * 2);
  f16x8*    w1s  = (f16x8*)alloc((size_t)4096 * 16);
  float*    als1 = (float*)alloc((size_t)N * 4 * 4);
  float*    ald1 = (float*)alloc((size_t)N * 4 * 4);
  int*      deg  = (int*)alloc((size_t)N * 4);
  int*      offs = (int*)alloc((size_t)(N + 1) * 4);
  int*      cur  = (int*)alloc((size_t)N * 4);
  int*      bsum = (int*)alloc((size_t)NB * 4);
  int*      boff = (int*)alloc((size_t)NB * 4);
  int*      csrs = (int*)alloc((size_t)ET * 4);
  int*      posa = (int*)alloc((size_t)ET * 4);
  float*    pw1  = (float*)alloc((size_t)ET * 4 * 4);
  float*    z    = (float*)alloc((size_t)N * 16 * 4);
  float*    als2 = (float*)alloc((size_t)N * 4);
  float*    ald2 = (float*)alloc((size_t)N * 4);
  float*    pw2  = (float*)alloc((size_t)ET * 4);

  hipMemsetAsync(deg, 0, (size_t)N * 4, stream);

  k_swzW<<<16, 256, 0, stream>>>(W1, w1s);
  k_gemm1f<<<(N + 63) / 64, 256, 0, stream>>>(x, w1s, as1, ad1, h16, als1, ald1, N);
  k_deg<<<(ET + 255) / 256, 256, 0, stream>>>(ei, deg, E, ET);
  k_scan_partial<<<NB, 256, 0, stream>>>(deg, bsum, N);
  k_scan_sums<<<1, 1, 0, stream>>>(bsum, boff, offs, NB, N);
  k_scan_final<<<NB, 256, 0, stream>>>(deg, boff, offs, cur, N);
  k_fill<<<(ET + 255) / 256, 256, 0, stream>>>(ei, cur, als1, ald1, csrs, pw1, posa, E, ET);
  k_agg1<<<(N + 7) / 8, 256, 0, stream>>>(offs, csrs, pw1, (const float4*)h16, b1, h2, N);
  k_gemm2<<<(N + 15) / 16, 256, 0, stream>>>(h2, W2, as2, ad2, z, als2, ald2, N);
  k_score2p<<<(ET + 255) / 256, 256, 0, stream>>>(ei, posa, als2, ald2, pw2, E, ET);
  k_agg2<<<(N + 15) / 16, 256, 0, stream>>>(offs, csrs, pw2, z, b2, out, N);
}